// Round 1
// 288.094 us; speedup vs baseline: 1.0307x; 1.0307x over previous
//
#include <hip/hip_runtime.h>

#define N_NODES 100000
#define N_EDGES 1600000
#define CAP 60         // per-node bucket capacity, mult. of 12 (Poisson(16): P(deg>60)~1e-16)
#define OVF_CAP 8192
#define GBLK 782       // ceil(100000/128) gemm blocks; also bin blocks (2048 edges)
#define NBIN 1563      // ceil(100000/64): bin = dst>>6 (one agg block per bin)
#define BINCAP2 1280   // Poisson(1024) + 8 sigma
#define FBLK 12500     // feat cvt blocks (float4: 3.2M threads)
#define ZROW 100000    // zero row index (padding gathers)

typedef unsigned int uint;
typedef unsigned short ushort;
typedef __attribute__((ext_vector_type(8))) short short8;  // 8 bf16 (4 VGPRs)
typedef __attribute__((ext_vector_type(4))) float f32x4;   // 4 fp32

__device__ __forceinline__ ushort f2bf(float f) {
  uint x = __float_as_uint(f);
  x += 0x7fffu + ((x >> 16) & 1u);  // round-to-nearest-even
  return (ushort)(x >> 16);
}
__device__ __forceinline__ float bflo(uint u) {
  return __uint_as_float(u << 16);
}
__device__ __forceinline__ float bfhi(uint u) {
  return __uint_as_float(u & 0xffff0000u);
}
// low/high 4 floats of a uint4 (8 bf16)
__device__ __forceinline__ f32x4 uplo(uint4 u) {
  return (f32x4){bflo(u.x), bfhi(u.x), bflo(u.y), bfhi(u.y)};
}
__device__ __forceinline__ f32x4 uphi(uint4 u) {
  return (f32x4){bflo(u.z), bfhi(u.z), bflo(u.w), bfhi(u.w)};
}

// ---------------- fused: edge binning + feat cvt + weight packing ----------
// Blocks [0,782): bin 2048 edges each into dense per-bin segments (LDS
// histogram -> global cursor atomics -> packed (src | dlow<<17) writes).
// Bin granularity = 64 nodes so each agg block scans ONLY its own edges.
// Blocks [782,13282): feat f32->bf16 (float4 loads). Then 192 blocks MFMA
// B-frag weight packing + 1 block zeroing the padding row fbf[100000].
__global__ __launch_bounds__(256) void k_pb(
    const int* __restrict__ src, const int* __restrict__ dst,
    const float* __restrict__ feat, const float* __restrict__ Ws0,
    const float* __restrict__ Wn0, const float* __restrict__ Ws1,
    const float* __restrict__ Wn1, uint* __restrict__ gcursor,
    uint* __restrict__ binbuf, int* __restrict__ ovf_cnt,
    int* __restrict__ ovf, uint* __restrict__ fbfu, ushort* __restrict__ wp0,
    ushort* __restrict__ wp1) {
  __shared__ uint hist[NBIN];
  __shared__ uint base[NBIN];
  int b = blockIdx.x;
  int tid = threadIdx.x;
  if (b < GBLK) {
    for (int i = tid; i < NBIN; i += 256) hist[i] = 0;
    __syncthreads();
    int e0 = b * 2048;
    uint val[8], bn[8], rk[8];
    int vld[8];
#pragma unroll
    for (int it = 0; it < 8; ++it) {
      int e = e0 + it * 256 + tid;
      vld[it] = (e < N_EDGES);
      if (vld[it]) {
        uint s = (uint)src[e];
        uint d = (uint)dst[e];
        bn[it] = d >> 6;
        rk[it] = atomicAdd(&hist[bn[it]], 1u);
        val[it] = s | ((d & 63u) << 17);
      }
    }
    __syncthreads();
    for (int i = tid; i < NBIN; i += 256)
      base[i] = hist[i] ? atomicAdd(&gcursor[i], hist[i]) : 0u;
    __syncthreads();
#pragma unroll
    for (int it = 0; it < 8; ++it) {
      if (!vld[it]) continue;
      uint p = base[bn[it]] + rk[it];
      if (p < BINCAP2) {
        binbuf[(size_t)bn[it] * BINCAP2 + p] = val[it];
      } else {  // ~never: segment overflow -> ovf, NOT counted (bit30=0)
        int o = atomicAdd(ovf_cnt, 1);
        if (o < OVF_CAP) {
          ovf[2 * o] = (int)(val[it] & 0x1FFFFu);
          ovf[2 * o + 1] = (int)(bn[it] * 64 + (val[it] >> 17));
        }
      }
    }
    return;
  }
  if (b < GBLK + FBLK) {  // feat conversion: float4 in, uint2 (4 bf16) out
    int i = (b - GBLK) * 256 + tid;
    float4 v = reinterpret_cast<const float4*>(feat)[i];
    uint2 o;
    o.x = (uint)f2bf(v.x) | ((uint)f2bf(v.y) << 16);
    o.y = (uint)f2bf(v.z) | ((uint)f2bf(v.w) << 16);
    reinterpret_cast<uint2*>(fbfu)[i] = o;
    return;
  }
  int wb = b - GBLK - FBLK;
  if (wb >= 192) {  // zero padding row fbf[100000] (gather target for tails)
    if (tid < 64) fbfu[ZROW * 64 + tid] = 0;
    return;
  }
  // B-frag layout (16x16x32 bf16): lane = 16q+c holds B[k=8q+j][n=16t+c].
  int idx = wb * 256 + tid;  // 49152 = 32768 + 16384
  if (idx < 32768) {
    int k = idx >> 7, n = idx & 127;
    float v = (k < 128) ? Ws0[k * 128 + n] : Wn0[(k - 128) * 128 + n];
    int s = k >> 5, q = (k >> 3) & 3, j = k & 7;
    int t = n >> 4, c = n & 15;
    wp0[(((s * 8 + t) * 64) + (q * 16 + c)) * 8 + j] = f2bf(v);
  } else {
    int i2 = idx - 32768;
    int k = i2 >> 7, n = i2 & 127;
    float v = (n < 64) ? Wn1[k * 64 + n] : Ws1[k * 64 + (n - 64)];
    int s = k >> 5, q = (k >> 3) & 3, j = k & 7;
    int t = n >> 4, c = n & 15;
    wp1[(((s * 8 + t) * 64) + (q * 16 + c)) * 8 + j] = f2bf(v);
  }
}

// ---------------- layer-0 aggregation (LDS bucket): 64 nodes/block ---------
// Phase 1: scan own bin's binbuf segment (~1024 edges, no filtering),
// scatter src ids into a 15KB LDS bucket pre-filled with ZROW.
// Phase 2: 16 lanes per node own the 256B row; 12-deep unconditional gather
// batches (12 dwordx4 in flight/lane, tail lanes hit the zero row).
__global__ __launch_bounds__(256) void k_agg0(
    const uint4* __restrict__ fbf4, const uint* __restrict__ binbuf,
    const uint* __restrict__ gcursor, int* __restrict__ ovf_cnt,
    int* __restrict__ ovf, uint4* __restrict__ agg4) {
  __shared__ __attribute__((aligned(16))) int lbkt[64 * CAP];
  __shared__ uint lcnt[64];
  int bb = blockIdx.x;
  int tid = threadIdx.x;
  if (tid < 64) lcnt[tid] = 0;
#pragma unroll
  for (int i = tid; i < 64 * CAP; i += 256) lbkt[i] = ZROW;
  __syncthreads();
  int ne = min((int)gcursor[bb], BINCAP2);
  for (int i = tid; i < ne; i += 256) {
    uint v = binbuf[(size_t)bb * BINCAP2 + i];
    int ldl = (int)(v >> 17);
    uint pos = atomicAdd(&lcnt[ldl], 1u);
    if (pos < CAP) {
      lbkt[ldl * CAP + pos] = (int)(v & 0x1FFFFu);
    } else {  // ~never: bucket spill -> ovf, already counted (bit30=1)
      int o = atomicAdd(ovf_cnt, 1);
      if (o < OVF_CAP) {
        ovf[2 * o] = (int)(v & 0x1FFFFu);
        ovf[2 * o + 1] = (bb * 64 + ldl) | (1 << 30);
      }
    }
  }
  __syncthreads();
  int g = tid >> 4, li = tid & 15;
  const int4* lb4 = reinterpret_cast<const int4*>(lbkt);
  int oc = min(*ovf_cnt, OVF_CAP);
#pragma unroll
  for (int p = 0; p < 4; ++p) {
    int nl = p * 16 + g;
    int n = bb * 64 + nl;
    int c = (int)lcnt[nl];
    int kb = min(c, CAP);
    f32x4 accA = (f32x4){0.f, 0.f, 0.f, 0.f};
    f32x4 accB = (f32x4){0.f, 0.f, 0.f, 0.f};
    for (int j = 0; j < kb; j += 12) {
      int4 ia = lb4[nl * 15 + (j >> 2)];
      int4 ib = lb4[nl * 15 + (j >> 2) + 1];
      int4 ic = lb4[nl * 15 + (j >> 2) + 2];
      uint4 u0 = fbf4[(size_t)ia.x * 16 + li];
      uint4 u1 = fbf4[(size_t)ia.y * 16 + li];
      uint4 u2 = fbf4[(size_t)ia.z * 16 + li];
      uint4 u3 = fbf4[(size_t)ia.w * 16 + li];
      uint4 u4 = fbf4[(size_t)ib.x * 16 + li];
      uint4 u5 = fbf4[(size_t)ib.y * 16 + li];
      uint4 u6 = fbf4[(size_t)ib.z * 16 + li];
      uint4 u7 = fbf4[(size_t)ib.w * 16 + li];
      uint4 u8 = fbf4[(size_t)ic.x * 16 + li];
      uint4 u9 = fbf4[(size_t)ic.y * 16 + li];
      uint4 ua = fbf4[(size_t)ic.z * 16 + li];
      uint4 ub = fbf4[(size_t)ic.w * 16 + li];
      accA += uplo(u0); accB += uphi(u0);
      accA += uplo(u1); accB += uphi(u1);
      accA += uplo(u2); accB += uphi(u2);
      accA += uplo(u3); accB += uphi(u3);
      accA += uplo(u4); accB += uphi(u4);
      accA += uplo(u5); accB += uphi(u5);
      accA += uplo(u6); accB += uphi(u6);
      accA += uplo(u7); accB += uphi(u7);
      accA += uplo(u8); accB += uphi(u8);
      accA += uplo(u9); accB += uphi(u9);
      accA += uplo(ua); accB += uphi(ua);
      accA += uplo(ub); accB += uphi(ub);
    }
    for (int i = 0; i < oc; ++i) {  // cold fallback path
      int df = ovf[2 * i + 1];
      if ((df & 0x1FFFF) == n) {
        uint4 u = fbf4[(size_t)ovf[2 * i] * 16 + li];
        accA += uplo(u);
        accB += uphi(u);
        c += ((df >> 30) & 1) ^ 1;
      }
    }
    float inv = 1.f / (float)max(c, 1);
    accA *= inv;
    accB *= inv;
    if (n < N_NODES) {
      uint4 o;
      o.x = (uint)f2bf(accA.x) | ((uint)f2bf(accA.y) << 16);
      o.y = (uint)f2bf(accA.z) | ((uint)f2bf(accA.w) << 16);
      o.z = (uint)f2bf(accB.x) | ((uint)f2bf(accB.y) << 16);
      o.w = (uint)f2bf(accB.z) | ((uint)f2bf(accB.w) << 16);
      agg4[(size_t)n * 16 + li] = o;
    }
  }
}

// ---------------- layer-0 MFMA GEMM: h = relu([feat|agg] @ Wp0 + b0) -------
// 128x128/block, 4 waves; wave = 64x64 = 4x4 C-frags; K=256 = 8 steps.
// aggb and h ALIAS (block reads own rows, overwrites post-barrier).
__global__ __launch_bounds__(256) void k_gemm0(
    const ushort* __restrict__ fbf, const ushort* aggb,
    const uint4* __restrict__ wp0g, const float* __restrict__ b0,
    ushort* h) {
  __shared__ uint4 wlds[4096];  // 64KB
  int tid = threadIdx.x;
#pragma unroll
  for (int i = 0; i < 16; ++i) wlds[i * 256 + tid] = wp0g[i * 256 + tid];
  __syncthreads();
  const short8* wl8 = reinterpret_cast<const short8*>(wlds);

  int lane = tid & 63, w = tid >> 6;
  int quad = lane >> 4, lm = lane & 15;
  int mw = blockIdx.x * 128 + (w >> 1) * 64;
  int tgb = (w & 1) * 4;

  f32x4 acc[4][4];
#pragma unroll
  for (int rt = 0; rt < 4; ++rt)
#pragma unroll
    for (int ct = 0; ct < 4; ++ct) acc[rt][ct] = (f32x4){0.f, 0.f, 0.f, 0.f};
  short8 az = {0, 0, 0, 0, 0, 0, 0, 0};

#pragma unroll
  for (int s = 0; s < 8; ++s) {
    const ushort* bsrc = (s < 4) ? fbf : aggb;
    int koff = (s & 3) * 32 + quad * 8;
    short8 a[4];
#pragma unroll
    for (int rt = 0; rt < 4; ++rt) {
      int row = mw + rt * 16 + lm;
      a[rt] = (row < N_NODES)
                  ? *reinterpret_cast<const short8*>(bsrc + (size_t)row * 128 + koff)
                  : az;
    }
#pragma unroll
    for (int ct = 0; ct < 4; ++ct) {
      short8 b = wl8[(s * 8 + tgb + ct) * 64 + lane];
#pragma unroll
      for (int rt = 0; rt < 4; ++rt)
        acc[rt][ct] =
            __builtin_amdgcn_mfma_f32_16x16x32_bf16(a[rt], b, acc[rt][ct], 0, 0, 0);
    }
  }

  __syncthreads();  // all waves done reading aggb before h overwrites
  float bv[4];
#pragma unroll
  for (int ct = 0; ct < 4; ++ct) bv[ct] = b0[(tgb + ct) * 16 + lm];
#pragma unroll
  for (int rt = 0; rt < 4; ++rt)
#pragma unroll
    for (int ct = 0; ct < 4; ++ct)
#pragma unroll
      for (int i = 0; i < 4; ++i) {
        int row = mw + rt * 16 + quad * 4 + i;
        if (row < N_NODES) {
          int col = (tgb + ct) * 16 + lm;
          h[(size_t)row * 128 + col] = f2bf(fmaxf(acc[rt][ct][i] + bv[ct], 0.f));
        }
      }
}

// ---------------- fused layer-1 MFMA GEMM: [hw | sout] = h @ Wp1 -----------
__global__ __launch_bounds__(256) void k_gemm1(
    const ushort* __restrict__ h, const uint4* __restrict__ wp1g,
    const float* __restrict__ b1, ushort* __restrict__ hw,
    float* __restrict__ out) {
  __shared__ uint4 wlds[2048];  // 32KB
  int tid = threadIdx.x;
  if (blockIdx.x == 0 && tid < 8)  // zero padding row hw[100000]
    reinterpret_cast<uint4*>(hw)[ZROW * 8 + tid] = make_uint4(0, 0, 0, 0);
#pragma unroll
  for (int i = 0; i < 8; ++i) wlds[i * 256 + tid] = wp1g[i * 256 + tid];
  __syncthreads();
  const short8* wl8 = reinterpret_cast<const short8*>(wlds);

  int lane = tid & 63, w = tid >> 6;
  int quad = lane >> 4, lm = lane & 15;
  int mw = blockIdx.x * 128 + (w >> 1) * 64;
  int tgb = (w & 1) * 4;

  f32x4 acc[4][4];
#pragma unroll
  for (int rt = 0; rt < 4; ++rt)
#pragma unroll
    for (int ct = 0; ct < 4; ++ct) acc[rt][ct] = (f32x4){0.f, 0.f, 0.f, 0.f};
  short8 az = {0, 0, 0, 0, 0, 0, 0, 0};

#pragma unroll
  for (int s = 0; s < 4; ++s) {
    int koff = s * 32 + quad * 8;
    short8 a[4];
#pragma unroll
    for (int rt = 0; rt < 4; ++rt) {
      int row = mw + rt * 16 + lm;
      a[rt] = (row < N_NODES)
                  ? *reinterpret_cast<const short8*>(h + (size_t)row * 128 + koff)
                  : az;
    }
#pragma unroll
    for (int ct = 0; ct < 4; ++ct) {
      short8 b = wl8[(s * 8 + tgb + ct) * 64 + lane];
#pragma unroll
      for (int rt = 0; rt < 4; ++rt)
        acc[rt][ct] =
            __builtin_amdgcn_mfma_f32_16x16x32_bf16(a[rt], b, acc[rt][ct], 0, 0, 0);
    }
  }

  if ((w & 1) == 0) {  // cols 0..63 -> hw = h@Wn1 (bf16)
#pragma unroll
    for (int rt = 0; rt < 4; ++rt)
#pragma unroll
      for (int ct = 0; ct < 4; ++ct)
#pragma unroll
        for (int i = 0; i < 4; ++i) {
          int row = mw + rt * 16 + quad * 4 + i;
          if (row < N_NODES)
            hw[(size_t)row * 64 + ct * 16 + lm] = f2bf(acc[rt][ct][i]);
        }
  } else {  // cols 64..127 -> out = h@Ws1 + b1 (f32)
    float bv[4];
#pragma unroll
    for (int ct = 0; ct < 4; ++ct) bv[ct] = b1[ct * 16 + lm];
#pragma unroll
    for (int rt = 0; rt < 4; ++rt)
#pragma unroll
      for (int ct = 0; ct < 4; ++ct)
#pragma unroll
        for (int i = 0; i < 4; ++i) {
          int row = mw + rt * 16 + quad * 4 + i;
          if (row < N_NODES)
            out[(size_t)row * 64 + ct * 16 + lm] = acc[rt][ct][i] + bv[ct];
        }
  }
}

// ---------------- layer-1 aggregation (LDS bucket): out[n] += mean ---------
// Same structure as k_agg0; 8 lanes per node own the 128B hw row.
__global__ __launch_bounds__(256) void k_agg1(
    const uint4* __restrict__ hw4, const uint* __restrict__ binbuf,
    const uint* __restrict__ gcursor, int* __restrict__ ovf_cnt,
    int* __restrict__ ovf, float* __restrict__ out) {
  __shared__ __attribute__((aligned(16))) int lbkt[64 * CAP];
  __shared__ uint lcnt[64];
  int bb = blockIdx.x;
  int tid = threadIdx.x;
  if (tid < 64) lcnt[tid] = 0;
#pragma unroll
  for (int i = tid; i < 64 * CAP; i += 256) lbkt[i] = ZROW;
  __syncthreads();
  int ne = min((int)gcursor[bb], BINCAP2);
  for (int i = tid; i < ne; i += 256) {
    uint v = binbuf[(size_t)bb * BINCAP2 + i];
    int ldl = (int)(v >> 17);
    uint pos = atomicAdd(&lcnt[ldl], 1u);
    if (pos < CAP) lbkt[ldl * CAP + pos] = (int)(v & 0x1FFFFu);
    // bucket spill already recorded in ovf by k_agg0's pass (bit30=1)
  }
  __syncthreads();
  int g = tid >> 3, li = tid & 7;
  const int4* lb4 = reinterpret_cast<const int4*>(lbkt);
  int oc = min(*ovf_cnt, OVF_CAP);
#pragma unroll
  for (int p = 0; p < 2; ++p) {
    int nl = p * 32 + g;
    int n = bb * 64 + nl;
    int c = (int)lcnt[nl];
    int kb = min(c, CAP);
    f32x4 accA = (f32x4){0.f, 0.f, 0.f, 0.f};
    f32x4 accB = (f32x4){0.f, 0.f, 0.f, 0.f};
    for (int j = 0; j < kb; j += 12) {
      int4 ia = lb4[nl * 15 + (j >> 2)];
      int4 ib = lb4[nl * 15 + (j >> 2) + 1];
      int4 ic = lb4[nl * 15 + (j >> 2) + 2];
      uint4 u0 = hw4[(size_t)ia.x * 8 + li];
      uint4 u1 = hw4[(size_t)ia.y * 8 + li];
      uint4 u2 = hw4[(size_t)ia.z * 8 + li];
      uint4 u3 = hw4[(size_t)ia.w * 8 + li];
      uint4 u4 = hw4[(size_t)ib.x * 8 + li];
      uint4 u5 = hw4[(size_t)ib.y * 8 + li];
      uint4 u6 = hw4[(size_t)ib.z * 8 + li];
      uint4 u7 = hw4[(size_t)ib.w * 8 + li];
      uint4 u8 = hw4[(size_t)ic.x * 8 + li];
      uint4 u9 = hw4[(size_t)ic.y * 8 + li];
      uint4 ua = hw4[(size_t)ic.z * 8 + li];
      uint4 ub = hw4[(size_t)ic.w * 8 + li];
      accA += uplo(u0); accB += uphi(u0);
      accA += uplo(u1); accB += uphi(u1);
      accA += uplo(u2); accB += uphi(u2);
      accA += uplo(u3); accB += uphi(u3);
      accA += uplo(u4); accB += uphi(u4);
      accA += uplo(u5); accB += uphi(u5);
      accA += uplo(u6); accB += uphi(u6);
      accA += uplo(u7); accB += uphi(u7);
      accA += uplo(u8); accB += uphi(u8);
      accA += uplo(u9); accB += uphi(u9);
      accA += uplo(ua); accB += uphi(ua);
      accA += uplo(ub); accB += uphi(ub);
    }
    for (int i = 0; i < oc; ++i) {  // cold fallback path
      int df = ovf[2 * i + 1];
      if ((df & 0x1FFFF) == n) {
        uint4 u = hw4[(size_t)ovf[2 * i] * 8 + li];
        accA += uplo(u);
        accB += uphi(u);
        c += ((df >> 30) & 1) ^ 1;
      }
    }
    if (n < N_NODES) {
      float inv = 1.f / (float)max(c, 1);
      float* op = out + (size_t)n * 64 + li * 8;
      float4 c0 = *reinterpret_cast<float4*>(op);
      float4 c1 = *reinterpret_cast<float4*>(op + 4);
      c0.x += accA.x * inv;
      c0.y += accA.y * inv;
      c0.z += accA.z * inv;
      c0.w += accA.w * inv;
      c1.x += accB.x * inv;
      c1.y += accB.y * inv;
      c1.z += accB.z * inv;
      c1.w += accB.w * inv;
      *reinterpret_cast<float4*>(op) = c0;
      *reinterpret_cast<float4*>(op + 4) = c1;
    }
  }
}

extern "C" void kernel_launch(void* const* d_in, const int* in_sizes, int n_in,
                              void* d_out, int out_size, void* d_ws,
                              size_t ws_size, hipStream_t stream) {
  const float* feat = (const float*)d_in[0];
  const int* src = (const int*)d_in[1];
  const int* dst = (const int*)d_in[2];
  const float* Ws0 = (const float*)d_in[3];
  const float* Wn0 = (const float*)d_in[4];
  const float* b0 = (const float*)d_in[5];
  const float* Ws1 = (const float*)d_in[6];
  const float* Wn1 = (const float*)d_in[7];
  const float* b1 = (const float*)d_in[8];
  char* ws = (char*)d_ws;

  // Workspace (59.38 MB <= 77.2 MB proven):
  //   hbuf    @ 0          : 25,600,000  (bf16 agg0, then h)
  //   ovf_cnt @ 25,600,000 :         64
  //   gcursor @ 25,600,064 :      6,336  (1563 bin cursors)
  //   ovf     @ 25,606,400 :     65,536
  //   binbuf  @ 25,671,936 :  8,002,560  (1563 x 1280 packed edges)
  //   feat_bf @ 33,674,496 : 25,600,256  (bf16 + zero row; hw reuses after gemm0)
  //   wp0     @ 59,274,752 :     65,536
  //   wp1     @ 59,340,288 :     32,768
  ushort* hbuf = (ushort*)(ws);
  int* ovf_cnt = (int*)(ws + 25600000);
  uint* gcursor = (uint*)(ws + 25600064);
  int* ovf = (int*)(ws + 25606400);
  uint* binbuf = (uint*)(ws + 25671936);
  ushort* fbf = (ushort*)(ws + 33674496);
  ushort* hw = (ushort*)(ws + 33674496);  // reuses feat_bf post-gemm0
  ushort* wp0 = (ushort*)(ws + 59274752);
  ushort* wp1 = (ushort*)(ws + 59340288);
  float* out = (float*)d_out;

  hipMemsetAsync(ws + 25600000, 0, 6400, stream);  // ovf_cnt + gcursor
  k_pb<<<GBLK + FBLK + 193, 256, 0, stream>>>(src, dst, feat, Ws0, Wn0, Ws1,
                                              Wn1, gcursor, binbuf, ovf_cnt,
                                              ovf, (uint*)fbf, wp0, wp1);
  k_agg0<<<NBIN, 256, 0, stream>>>((const uint4*)fbf, binbuf, gcursor, ovf_cnt,
                                   ovf, (uint4*)hbuf);
  k_gemm0<<<GBLK, 256, 0, stream>>>(fbf, hbuf, (const uint4*)wp0, b0, hbuf);
  k_gemm1<<<GBLK, 256, 0, stream>>>(hbuf, (const uint4*)wp1, b1, hw, out);
  k_agg1<<<NBIN, 256, 0, stream>>>((const uint4*)hw, binbuf, gcursor, ovf_cnt,
                                   ovf, out);
}